// Round 12
// baseline (531.850 us; speedup 1.0000x reference)
//
#include <hip/hip_runtime.h>
#include <hip/hip_bf16.h>

#define B_ 4
#define S_ 128
#define D_ 512
#define H_ 8
#define DH_ 64
#define F_ 2048
#define R_ 8
#define NB 256
#define BSDc 262144   // B*S*D
#define E2c 262144    // 512*512

typedef unsigned short ush;
typedef __attribute__((ext_vector_type(8))) short short8;
typedef __attribute__((ext_vector_type(4))) float f32x4;

__device__ __forceinline__ void split2(float a, ush& h, ush& l) {
    unsigned u = __float_as_uint(a);
    unsigned hr = (u + 0x7FFFu + ((u >> 16) & 1u)) >> 16;
    h = (ush)hr;
    float lo = a - __uint_as_float(hr << 16);
    unsigned u2 = __float_as_uint(lo);
    l = (ush)((u2 + 0x7FFFu + ((u2 >> 16) & 1u)) >> 16);
}

struct TDesc { const float* s; ush* h; ush* l; int K; int N; int off; };

struct Args {
    const float *x, *ln1_g, *ln1_b, *bq, *bk, *bv, *bo, *b1, *b2;
    const float *rc_b1, *rc_w2, *rc_b2, *s2n_b, *ln2_g, *ln2_b;
    const ush *qkv_h, *qkv_l, *wo_h, *wo_l, *w1_h, *w1_l, *w2_h, *w2_l;
    const ush *rcT_h, *rcT_l, *s2_h, *s2_l;
    float *q, *nu, *apart, *y, *P;
    ush *xnh, *xnl, *ctxh, *ctxl, *aoh, *aol, *hidh, *hidl, *nuh, *nul, *rsh, *rsl;
    int *rel, *ecount, *elist, *cnt;
    float *out;
    TDesc td[16];
    int ntp;
};

// grid barrier: monotonic counter, agent-scope atomics + fences (cross-XCD safe)
__device__ __forceinline__ void gbar(int* cnt, int phase) {
    __syncthreads();
    if (threadIdx.x == 0) {
        __builtin_amdgcn_fence(__ATOMIC_RELEASE, "agent");
        __hip_atomic_fetch_add(cnt, 1, __ATOMIC_RELAXED, __HIP_MEMORY_SCOPE_AGENT);
        while (__hip_atomic_load(cnt, __ATOMIC_RELAXED, __HIP_MEMORY_SCOPE_AGENT) < NB * phase)
            __builtin_amdgcn_s_sleep(2);
        __builtin_amdgcn_fence(__ATOMIC_ACQUIRE, "agent");
    }
    __syncthreads();
}

// ---- MFMA bf16x3 64x64 tile core, BK=32 (r8-proven), LDS = 4 x 64 x 36 ush = 18432 B ----
#define RPB 36
__device__ __forceinline__ void bb_tile(const ush* __restrict__ Ath, const ush* __restrict__ Atl,
                                        const ush* __restrict__ Bth, const ush* __restrict__ Btl,
                                        int K, int rowBase, int colBase, int kStart, int kLen,
                                        f32x4 acc[2][2], ush* sm) {
    ush (*Ah)[RPB] = (ush(*)[RPB])sm;
    ush (*Al)[RPB] = (ush(*)[RPB])(sm + 64 * RPB);
    ush (*Bh)[RPB] = (ush(*)[RPB])(sm + 128 * RPB);
    ush (*Bl)[RPB] = (ush(*)[RPB])(sm + 192 * RPB);
    int tid = threadIdx.x;
    int w = tid >> 6, lane = tid & 63;
    int lm = lane & 15, quad = lane >> 4;
    int wm = (w & 1) * 32, wn = (w >> 1) * 32;
    int sRow = tid >> 2, sCh = (tid & 3) * 8;
    const size_t aoff = (size_t)(rowBase + sRow) * K + sCh + kStart;
    const size_t boff = (size_t)(colBase + sRow) * K + sCh + kStart;
    int nIter = kLen / 32;
    short8 pah = *(const short8*)&Ath[aoff];
    short8 pal = *(const short8*)&Atl[aoff];
    short8 pbh = *(const short8*)&Bth[boff];
    short8 pbl = *(const short8*)&Btl[boff];
    for (int it = 0; it < nIter; ++it) {
        *(short8*)&Ah[sRow][sCh] = pah;
        *(short8*)&Al[sRow][sCh] = pal;
        *(short8*)&Bh[sRow][sCh] = pbh;
        *(short8*)&Bl[sRow][sCh] = pbl;
        __syncthreads();
        if (it + 1 < nIter) {
            size_t ka = (size_t)(it + 1) * 32;
            pah = *(const short8*)&Ath[aoff + ka];
            pal = *(const short8*)&Atl[aoff + ka];
            pbh = *(const short8*)&Bth[boff + ka];
            pbl = *(const short8*)&Btl[boff + ka];
        }
        short8 ah[2], al[2], bh[2], bl[2];
#pragma unroll
        for (int t = 0; t < 2; ++t) {
            ah[t] = *(const short8*)&Ah[wm + t * 16 + lm][quad * 8];
            al[t] = *(const short8*)&Al[wm + t * 16 + lm][quad * 8];
            bh[t] = *(const short8*)&Bh[wn + t * 16 + lm][quad * 8];
            bl[t] = *(const short8*)&Bl[wn + t * 16 + lm][quad * 8];
        }
#pragma unroll
        for (int tm = 0; tm < 2; ++tm)
#pragma unroll
            for (int tn = 0; tn < 2; ++tn) {
                acc[tm][tn] = __builtin_amdgcn_mfma_f32_16x16x32_bf16(ah[tm], bh[tn], acc[tm][tn], 0, 0, 0);
                acc[tm][tn] = __builtin_amdgcn_mfma_f32_16x16x32_bf16(ah[tm], bl[tn], acc[tm][tn], 0, 0, 0);
                acc[tm][tn] = __builtin_amdgcn_mfma_f32_16x16x32_bf16(al[tm], bh[tn], acc[tm][tn], 0, 0, 0);
            }
        __syncthreads();
    }
}

__device__ __forceinline__ void epi_f32(f32x4 acc[2][2], float* C, int N, const float* bias,
                                        int rowBase, int colBase) {
    int tid = threadIdx.x;
    int w = tid >> 6, lane = tid & 63;
    int lm = lane & 15, quad = lane >> 4;
    int wm = (w & 1) * 32, wn = (w >> 1) * 32;
#pragma unroll
    for (int tm = 0; tm < 2; ++tm)
#pragma unroll
        for (int tn = 0; tn < 2; ++tn) {
            int col = colBase + wn + tn * 16 + lm;
            float bi = bias ? bias[col] : 0.f;
#pragma unroll
            for (int r = 0; r < 4; ++r) {
                int row = rowBase + wm + tm * 16 + quad * 4 + r;
                C[(size_t)row * N + col] = acc[tm][tn][r] + bi;
            }
        }
}

__device__ __forceinline__ void epi_b16(f32x4 acc[2][2], ush* Ch, ush* Cl, int N,
                                        const float* bias, int relu, int rowBase, int colBase) {
    int tid = threadIdx.x;
    int w = tid >> 6, lane = tid & 63;
    int lm = lane & 15, quad = lane >> 4;
    int wm = (w & 1) * 32, wn = (w >> 1) * 32;
#pragma unroll
    for (int tm = 0; tm < 2; ++tm)
#pragma unroll
        for (int tn = 0; tn < 2; ++tn) {
            int col = colBase + wn + tn * 16 + lm;
            float bi = bias ? bias[col] : 0.f;
#pragma unroll
            for (int r = 0; r < 4; ++r) {
                int row = rowBase + wm + tm * 16 + quad * 4 + r;
                float v = acc[tm][tn][r] + bi;
                if (relu) v = fmaxf(v, 0.f);
                ush h, l;
                split2(v, h, l);
                Ch[(size_t)row * N + col] = h;
                Cl[(size_t)row * N + col] = l;
            }
        }
}

__global__ __launch_bounds__(256) void mega_kernel(Args a) {
    __shared__ __align__(16) unsigned char smem[18432];
    int tid = threadIdx.x;
    int w = tid >> 6, lane = tid & 63;
    int phase = 0;
    ush* gsm = (ush*)smem;

    // ---- S0a: weight transpose + bf16 hi/lo split ----
    {
        float (*sm)[33] = (float(*)[33])smem;
        int col = tid & 31, rg = tid >> 5;
        for (int t = blockIdx.x; t < a.ntp; t += NB) {
            int wi = 0;
#pragma unroll
            for (int i = 1; i < 16; ++i) if (t >= a.td[i].off) wi = i;
            TDesc dd = a.td[wi];
            int tt = t - dd.off;
            int ntk = dd.K / 32;
            int tk = tt % ntk, tn2 = tt / ntk;
            int k0 = tk * 32, n0 = tn2 * 32;
#pragma unroll
            for (int i = 0; i < 4; ++i)
                sm[rg * 4 + i][col] = dd.s[(size_t)(k0 + rg * 4 + i) * dd.N + n0 + col];
            __syncthreads();
#pragma unroll
            for (int i = 0; i < 4; ++i) {
                int n = n0 + rg * 4 + i, k = k0 + col;
                ush h, l;
                split2(sm[col][rg * 4 + i], h, l);
                dd.h[(size_t)n * dd.K + k] = h;
                dd.l[(size_t)n * dd.K + k] = l;
            }
            __syncthreads();
        }
    }
    // ---- S0b: LN1 -> xn hi/lo ----
    {
        float* red = (float*)smem;
        for (int row = blockIdx.x; row < 512; row += NB) {
            const float* xr = a.x + (size_t)row * D_;
            float v0 = xr[tid], v1 = xr[tid + 256];
            red[tid] = v0 + v1;
            __syncthreads();
            for (int off = 128; off > 0; off >>= 1) {
                if (tid < off) red[tid] += red[tid + off];
                __syncthreads();
            }
            float mean = red[0] * (1.0f / D_);
            __syncthreads();
            float d0 = v0 - mean, d1 = v1 - mean;
            red[tid] = d0 * d0 + d1 * d1;
            __syncthreads();
            for (int off = 128; off > 0; off >>= 1) {
                if (tid < off) red[tid] += red[tid + off];
                __syncthreads();
            }
            float rs = rsqrtf(red[0] * (1.0f / D_) + 1e-5f);
            float o0 = d0 * rs * a.ln1_g[tid] + a.ln1_b[tid];
            float o1 = d1 * rs * a.ln1_g[tid + 256] + a.ln1_b[tid + 256];
            ush h, l;
            split2(o0, h, l); a.xnh[(size_t)row * D_ + tid] = h; a.xnl[(size_t)row * D_ + tid] = l;
            split2(o1, h, l); a.xnh[(size_t)row * D_ + tid + 256] = h; a.xnl[(size_t)row * D_ + tid + 256] = l;
            __syncthreads();
        }
    }
    gbar(a.cnt, ++phase);

    // ---- S1: QKV (192 tiles) ----
    for (int t = blockIdx.x; t < 192; t += NB) {
        int z = t >> 6, rem = t & 63, ty = rem >> 3, tx = rem & 7;
        f32x4 acc[2][2] = {};
        bb_tile(a.xnh, a.xnl, a.qkv_h + (size_t)z * E2c, a.qkv_l + (size_t)z * E2c,
                512, ty * 64, tx * 64, 0, 512, acc, gsm);
        const float* bias = (z == 0) ? a.bq : (z == 1) ? a.bk : a.bv;
        epi_f32(acc, a.q + (size_t)z * BSDc, 512, bias, ty * 64, tx * 64);
    }
    gbar(a.cnt, ++phase);

    // ---- S2: attention + adjacency (512 units, 2 per block) ----
    {
        float (*qsm)[64] = (float(*)[64])smem;
        float (*psm)[128] = (float(*)[128])(smem + 2048);
        const float* kk = a.q + (size_t)BSDc;
        const float* vv = a.q + (size_t)2 * BSDc;
        for (int it = 0; it < 2; ++it) {
            int bi = blockIdx.x + it * NB;
            int i = bi & 127, b = bi >> 7;
#pragma unroll
            for (int hh = 0; hh < 2; ++hh) {
                int h = w + hh * 4;
                qsm[h][lane] = a.q[(size_t)bi * D_ + h * 64 + lane];
            }
            __syncthreads();
#pragma unroll
            for (int hh = 0; hh < 2; ++hh) {
                int h = w + hh * 4;
                const float* k0p = kk + (size_t)(b * 128 + lane) * D_ + h * 64;
                const float* k1p = k0p + (size_t)64 * D_;
                float s0 = 0.f, s1 = 0.f;
#pragma unroll 8
                for (int d = 0; d < 64; ++d) {
                    float qd = qsm[h][d];
                    s0 += qd * k0p[d];
                    s1 += qd * k1p[d];
                }
                s0 *= 0.125f; s1 *= 0.125f;
                float m = fmaxf(s0, s1);
#pragma unroll
                for (int off = 32; off > 0; off >>= 1) m = fmaxf(m, __shfl_xor(m, off));
                float e0 = __expf(s0 - m), e1 = __expf(s1 - m);
                float sum = e0 + e1;
#pragma unroll
                for (int off = 32; off > 0; off >>= 1) sum += __shfl_xor(sum, off);
                float inv = 1.f / sum;
                psm[h][lane] = e0 * inv;
                psm[h][lane + 64] = e1 * inv;
            }
            __syncthreads();
            if (tid < 128) {
                int j = tid;
                float s = psm[0][j] + psm[1][j] + psm[2][j] + psm[3][j]
                        + psm[4][j] + psm[5][j] + psm[6][j] + psm[7][j];
                s *= 0.125f;
                if (s > 0.1f && j != i) {
                    int p = atomicAdd(a.ecount, 1);
                    a.elist[p] = (bi << 7) | j;
                }
            }
#pragma unroll
            for (int hh = 0; hh < 2; ++hh) {
                int h = w + hh * 4;
                const float* vb = vv + (size_t)(b * 128) * D_ + h * 64 + lane;
                float acc = 0.f;
                for (int j = 0; j < 128; ++j) acc += psm[h][j] * vb[(size_t)j * D_];
                ush hq, lq;
                split2(acc, hq, lq);
                a.ctxh[(size_t)bi * D_ + h * 64 + lane] = hq;
                a.ctxl[(size_t)bi * D_ + h * 64 + lane] = lq;
            }
            __syncthreads();
        }
    }
    gbar(a.cnt, ++phase);

    // ---- S3: wo (64 tiles) ----
    for (int t = blockIdx.x; t < 64; t += NB) {
        int ty = t >> 3, tx = t & 7;
        f32x4 acc[2][2] = {};
        bb_tile(a.ctxh, a.ctxl, a.wo_h, a.wo_l, 512, ty * 64, tx * 64, 0, 512, acc, gsm);
        epi_b16(acc, a.aoh, a.aol, 512, a.bo, 0, ty * 64, tx * 64);
    }
    gbar(a.cnt, ++phase);

    // ---- S4: FFN1 relu (256 tiles, N=2048) ----
    for (int t = blockIdx.x; t < 256; t += NB) {
        int ty = t >> 5, tx = t & 31;
        f32x4 acc[2][2] = {};
        bb_tile(a.aoh, a.aol, a.w1_h, a.w1_l, 512, ty * 64, tx * 64, 0, 512, acc, gsm);
        epi_b16(acc, a.hidh, a.hidl, 2048, a.b1, 1, ty * 64, tx * 64);
    }
    gbar(a.cnt, ++phase);

    // ---- S5: FFN2 split-K=4 partials (256 tiles, K=2048) ----
    for (int t = blockIdx.x; t < 256; t += NB) {
        int kz = t >> 6, rem = t & 63, ty = rem >> 3, tx = rem & 7;
        f32x4 acc[2][2] = {};
        bb_tile(a.hidh, a.hidl, a.w2_h, a.w2_l, 2048, ty * 64, tx * 64, kz * 512, 512, acc, gsm);
        epi_f32(acc, a.P + (size_t)kz * BSDc, 512, (const float*)0, ty * 64, tx * 64);
    }
    gbar(a.cnt, ++phase);

    // ---- S6: reduce partials + b2 -> nu fp32 + hi/lo (65536 float4s, 1/thread) ----
    {
        int i4 = blockIdx.x * 256 + tid;
        float4 p0 = ((const float4*)a.P)[i4];
        float4 p1 = ((const float4*)(a.P + (size_t)BSDc))[i4];
        float4 p2 = ((const float4*)(a.P + (size_t)2 * BSDc))[i4];
        float4 p3 = ((const float4*)(a.P + (size_t)3 * BSDc))[i4];
        int col4 = (i4 * 4) & (D_ - 1);
        float4 bi = *(const float4*)&a.b2[col4];
        float4 r;
        r.x = p0.x + p1.x + p2.x + p3.x + bi.x;
        r.y = p0.y + p1.y + p2.y + p3.y + bi.y;
        r.z = p0.z + p1.z + p2.z + p3.z + bi.z;
        r.w = p0.w + p1.w + p2.w + p3.w + bi.w;
        ((float4*)a.nu)[i4] = r;
        ush h[4], l[4];
        split2(r.x, h[0], l[0]); split2(r.y, h[1], l[1]);
        split2(r.z, h[2], l[2]); split2(r.w, h[3], l[3]);
        *(unsigned long long*)&a.nuh[i4 * 4] =
            (unsigned long long)h[0] | ((unsigned long long)h[1] << 16)
          | ((unsigned long long)h[2] << 32) | ((unsigned long long)h[3] << 48);
        *(unsigned long long*)&a.nul[i4 * 4] =
            (unsigned long long)l[0] | ((unsigned long long)l[1] << 16)
          | ((unsigned long long)l[2] << 32) | ((unsigned long long)l[3] << 48);
    }
    gbar(a.cnt, ++phase);

    // ---- S7: rc halves + T[r] (576 tiles, z=0..8) ----
    for (int t = blockIdx.x; t < 576; t += NB) {
        int z = t >> 6, rem = t & 63, ty = rem >> 3, tx = rem & 7;
        f32x4 acc[2][2] = {};
        bb_tile(a.nuh, a.nul, a.rcT_h + (size_t)z * E2c, a.rcT_l + (size_t)z * E2c,
                512, ty * 64, tx * 64, 0, 512, acc, gsm);
        epi_f32(acc, a.apart + (size_t)z * BSDc, 512, (const float*)0, ty * 64, tx * 64);
    }
    gbar(a.cnt, ++phase);

    // ---- S8: relation classifier over compacted edges (wave per edge) ----
    {
        int n = *a.ecount;
        const float* b_part = a.apart + (size_t)BSDc;
        for (int e = blockIdx.x * 4 + w; e < n; e += NB * 4) {
            int idx = a.elist[e];
            int vv2 = idx & 127;
            int bu = idx >> 7;
            int u = bu & 127, b = bu >> 7;
            const float* ap = a.apart + (size_t)(b * 128 + u) * D_;
            const float* bp = b_part + (size_t)(b * 128 + vv2) * D_;
            float lp[R_];
#pragma unroll
            for (int r = 0; r < R_; ++r) lp[r] = 0.f;
#pragma unroll
            for (int jj = 0; jj < D_ / 64; ++jj) {
                int d = lane + jj * 64;
                float hv = fmaxf(ap[d] + bp[d] + a.rc_b1[d], 0.f);
#pragma unroll
                for (int r = 0; r < R_; ++r) lp[r] += hv * a.rc_w2[d * R_ + r];
            }
#pragma unroll
            for (int r = 0; r < R_; ++r) {
#pragma unroll
                for (int off = 32; off > 0; off >>= 1) lp[r] += __shfl_down(lp[r], off);
            }
            if (lane == 0) {
                float best = lp[0] + a.rc_b2[0];
                int bi = 0;
#pragma unroll
                for (int r = 1; r < R_; ++r) {
                    float L = lp[r] + a.rc_b2[r];
                    if (L > best) { best = L; bi = r; }
                }
                a.rel[idx] = bi;
            }
        }
    }
    gbar(a.cnt, ++phase);

    // ---- S9: aggregate reasoned = nu + sum_edges T -> rs hi/lo (512 units) ----
    {
        int* rl = (int*)smem;
        const float* T = a.apart + (size_t)2 * BSDc;
        for (int blk = blockIdx.x; blk < 512; blk += NB) {
            int vv2 = blk & 127, b = blk >> 7;
            if (tid < 128) rl[tid] = a.rel[(size_t)(b * 128 + tid) * 128 + vv2];
            __syncthreads();
            float2 acc2 = ((const float2*)(a.nu + (size_t)blk * D_))[tid];
            for (int u = 0; u < 128; ++u) {
                int r = rl[u];
                if (r > 0) {
                    float2 tv = ((const float2*)(T + (size_t)(r - 1) * BSDc
                                                 + (size_t)(b * 128 + u) * D_))[tid];
                    acc2.x += tv.x; acc2.y += tv.y;
                }
            }
            ush h0, l0, h1, l1;
            split2(acc2.x, h0, l0);
            split2(acc2.y, h1, l1);
            size_t o = (size_t)blk * D_ + tid * 2;
            *(unsigned*)&a.rsh[o] = (unsigned)h0 | ((unsigned)h1 << 16);
            *(unsigned*)&a.rsl[o] = (unsigned)l0 | ((unsigned)l1 << 16);
            __syncthreads();
        }
    }
    gbar(a.cnt, ++phase);

    // ---- S10: s2n (64 tiles) ----
    for (int t = blockIdx.x; t < 64; t += NB) {
        int ty = t >> 3, tx = t & 7;
        f32x4 acc[2][2] = {};
        bb_tile(a.rsh, a.rsl, a.s2_h, a.s2_l, 512, ty * 64, tx * 64, 0, 512, acc, gsm);
        epi_f32(acc, a.y, 512, a.s2n_b, ty * 64, tx * 64);
    }
    gbar(a.cnt, ++phase);

    // ---- S11: LN2 -> out ----
    {
        float* red = (float*)smem;
        for (int row = blockIdx.x; row < 512; row += NB) {
            float v0 = a.x[(size_t)row * D_ + tid]       + a.y[(size_t)row * D_ + tid];
            float v1 = a.x[(size_t)row * D_ + tid + 256] + a.y[(size_t)row * D_ + tid + 256];
            red[tid] = v0 + v1;
            __syncthreads();
            for (int off = 128; off > 0; off >>= 1) {
                if (tid < off) red[tid] += red[tid + off];
                __syncthreads();
            }
            float mean = red[0] * (1.0f / D_);
            __syncthreads();
            float d0 = v0 - mean, d1 = v1 - mean;
            red[tid] = d0 * d0 + d1 * d1;
            __syncthreads();
            for (int off = 128; off > 0; off >>= 1) {
                if (tid < off) red[tid] += red[tid + off];
                __syncthreads();
            }
            float rs = rsqrtf(red[0] * (1.0f / D_) + 1e-5f);
            a.out[(size_t)row * D_ + tid]       = d0 * rs * a.ln2_g[tid]       + a.ln2_b[tid];
            a.out[(size_t)row * D_ + tid + 256] = d1 * rs * a.ln2_g[tid + 256] + a.ln2_b[tid + 256];
            __syncthreads();
        }
    }
}

extern "C" void kernel_launch(void* const* d_in, const int* in_sizes, int n_in,
                              void* d_out, int out_size, void* d_ws, size_t ws_size,
                              hipStream_t stream) {
    const float* x     = (const float*)d_in[0];
    const float* ln1_g = (const float*)d_in[1];
    const float* ln1_b = (const float*)d_in[2];
    const float* wq    = (const float*)d_in[3];
    const float* bq    = (const float*)d_in[4];
    const float* wk    = (const float*)d_in[5];
    const float* bk    = (const float*)d_in[6];
    const float* wv    = (const float*)d_in[7];
    const float* bv    = (const float*)d_in[8];
    const float* wo    = (const float*)d_in[9];
    const float* bo    = (const float*)d_in[10];
    const float* w1    = (const float*)d_in[11];
    const float* b1    = (const float*)d_in[12];
    const float* w2    = (const float*)d_in[13];
    const float* b2    = (const float*)d_in[14];
    const float* rc_w1 = (const float*)d_in[15];
    const float* rc_b1 = (const float*)d_in[16];
    const float* rc_w2 = (const float*)d_in[17];
    const float* rc_b2 = (const float*)d_in[18];
    const float* kg_w  = (const float*)d_in[19];
    const float* s2n_w = (const float*)d_in[20];
    const float* s2n_b = (const float*)d_in[21];
    const float* ln2_g = (const float*)d_in[22];
    const float* ln2_b = (const float*)d_in[23];

    const int BS  = B_ * S_;
    const int BSD = BSDc;
    const size_t E = E2c;

    // ---- Workspace layout (same family as r11, + cnt) ----
    ush* wt = (ush*)d_ws;
    ush* qkv_h = wt;
    ush* qkv_l = wt + 3 * E;
    ush* wo_h  = wt + 6 * E;
    ush* wo_l  = wt + 7 * E;
    ush* w1_h  = wt + 8 * E;
    ush* w1_l  = wt + 12 * E;
    ush* w2_h  = wt + 16 * E;
    ush* w2_l  = wt + 20 * E;
    ush* rcT_h = wt + 24 * E;     // 9E: rc half0, half1, kg r=1..7
    ush* rcT_l = wt + 33 * E;
    ush* s2_h  = wt + 42 * E;
    ush* s2_l  = wt + 43 * E;

    int* rel    = (int*)(wt + 44 * E);    // zeroed
    int* ecount = rel + B_ * S_ * S_;     // zeroed (cnt lives at ecount+1, inside zeroed range)
    int* cnt    = ecount + 1;
    int* elist  = ecount + 64;
    float* fp = (float*)(elist + B_ * S_ * S_);
    float* q      = fp;                       // 3 BSD (q,k,v)
    float* nu     = fp + (size_t)3 * BSD;
    float* apart  = fp + (size_t)4 * BSD;     // a_part, b_part, T[0..6]  (9 BSD)
    float* y      = fp + (size_t)13 * BSD;
    float* Pbuf   = fp + (size_t)14 * BSD;    // 4 BSD
    ush* act = (ush*)(fp + (size_t)18 * BSD);
    ush* xnh  = act;
    ush* xnl  = act + (size_t)BSD;
    ush* ctxh = act + (size_t)2 * BSD;
    ush* ctxl = act + (size_t)3 * BSD;
    ush* aoh  = act + (size_t)4 * BSD;
    ush* aol  = act + (size_t)5 * BSD;
    ush* nuh  = act + (size_t)6 * BSD;
    ush* nul  = act + (size_t)7 * BSD;
    ush* rsh  = act + (size_t)8 * BSD;
    ush* rsl  = act + (size_t)9 * BSD;
    ush* hidh = act + (size_t)10 * BSD;       // BS*F each
    ush* hidl = hidh + (size_t)BS * F_;

    // zero rel + ecount + cnt (+ padding)
    hipMemsetAsync(rel, 0, (size_t)(B_ * S_ * S_ + 64) * 4, stream);

    Args a;
    a.x = x; a.ln1_g = ln1_g; a.ln1_b = ln1_b;
    a.bq = bq; a.bk = bk; a.bv = bv; a.bo = bo; a.b1 = b1; a.b2 = b2;
    a.rc_b1 = rc_b1; a.rc_w2 = rc_w2; a.rc_b2 = rc_b2; a.s2n_b = s2n_b;
    a.ln2_g = ln2_g; a.ln2_b = ln2_b;
    a.qkv_h = qkv_h; a.qkv_l = qkv_l; a.wo_h = wo_h; a.wo_l = wo_l;
    a.w1_h = w1_h; a.w1_l = w1_l; a.w2_h = w2_h; a.w2_l = w2_l;
    a.rcT_h = rcT_h; a.rcT_l = rcT_l; a.s2_h = s2_h; a.s2_l = s2_l;
    a.q = q; a.nu = nu; a.apart = apart; a.y = y; a.P = Pbuf;
    a.xnh = xnh; a.xnl = xnl; a.ctxh = ctxh; a.ctxl = ctxl;
    a.aoh = aoh; a.aol = aol; a.hidh = hidh; a.hidl = hidl;
    a.nuh = nuh; a.nul = nul; a.rsh = rsh; a.rsl = rsl;
    a.rel = rel; a.ecount = ecount; a.elist = elist; a.cnt = cnt;
    a.out = (float*)d_out;

    int off = 0;
    auto setd = [&](int i, const float* s, ush* h, ush* l, int K, int N) {
        a.td[i] = TDesc{s, h, l, K, N, off};
        off += (K / 32) * (N / 32);
    };
    setd(0, wq, qkv_h,         qkv_l,         D_, D_);
    setd(1, wk, qkv_h + E,     qkv_l + E,     D_, D_);
    setd(2, wv, qkv_h + 2 * E, qkv_l + 2 * E, D_, D_);
    setd(3, wo, wo_h, wo_l, D_, D_);
    setd(4, w1, w1_h, w1_l, D_, F_);
    setd(5, w2, w2_h, w2_l, F_, D_);
    setd(6, rc_w1,            rcT_h,     rcT_l,     D_, D_);
    setd(7, rc_w1 + D_ * D_,  rcT_h + E, rcT_l + E, D_, D_);
    setd(8, s2n_w, s2_h, s2_l, D_, D_);
    for (int r = 1; r < R_; ++r)
        setd(8 + r, kg_w + (size_t)r * D_ * D_, rcT_h + (size_t)(r + 1) * E,
             rcT_l + (size_t)(r + 1) * E, D_, D_);
    a.ntp = off;

    hipLaunchKernelGGL(mega_kernel, dim3(NB), dim3(256), 0, stream, a);
}

// Round 13
// 294.982 us; speedup vs baseline: 1.8030x; 1.8030x over previous
//
#include <hip/hip_runtime.h>
#include <hip/hip_bf16.h>

#define B_ 4
#define S_ 128
#define D_ 512
#define H_ 8
#define DH_ 64
#define F_ 2048
#define R_ 8

typedef __attribute__((ext_vector_type(8))) short short8;
typedef __attribute__((ext_vector_type(4))) float f32x4;

// fp32 -> bf16 hi (RNE) + bf16 lo (RNE of exact residual)
__device__ __forceinline__ void split2(float a, unsigned short& h, unsigned short& l) {
    unsigned u = __float_as_uint(a);
    unsigned hr = (u + 0x7FFFu + ((u >> 16) & 1u)) >> 16;
    h = (unsigned short)hr;
    float lo = a - __uint_as_float(hr << 16);
    unsigned u2 = __float_as_uint(lo);
    l = (unsigned short)((u2 + 0x7FFFu + ((u2 >> 16) & 1u)) >> 16);
}

// ---------------- weight transpose + bf16 hi/lo split ----------------
struct TDesc { const float* s; unsigned short* h; unsigned short* l; int K; int N; int off; };
struct TPack { TDesc d[10]; };

__global__ void transpose_split_kernel(TPack p) {
    __shared__ float sm[32][33];
    int bid = blockIdx.x;
    int wi = 0;
#pragma unroll
    for (int i = 1; i < 10; ++i) if (bid >= p.d[i].off) wi = i;
    const TDesc dd = p.d[wi];
    int t = bid - dd.off;
    int ntk = dd.K / 32;
    int tk = t % ntk, tn = t / ntk;
    int k0 = tk * 32, n0 = tn * 32;
    int col = threadIdx.x & 31, rg = threadIdx.x >> 5;   // rg 0..7
#pragma unroll
    for (int i = 0; i < 4; ++i) {
        int row = rg * 4 + i;
        sm[row][col] = dd.s[(size_t)(k0 + row) * dd.N + n0 + col];
    }
    __syncthreads();
#pragma unroll
    for (int i = 0; i < 4; ++i) {
        int n = n0 + rg * 4 + i;
        int k = k0 + col;
        float v = sm[col][rg * 4 + i];
        unsigned short h, l;
        split2(v, h, l);
        dd.h[(size_t)n * dd.K + k] = h;
        dd.l[(size_t)n * dd.K + k] = l;
    }
}

// ---------------- MFMA bf16x3 GEMM core ----------------
#define RP 40   // LDS row pitch in ushorts (32 + 8 pad)

__device__ __forceinline__ void mgemm_core(const float* __restrict__ A,
                                           const unsigned short* __restrict__ Bth,
                                           const unsigned short* __restrict__ Btl,
                                           int K, int rowBase, int colBase,
                                           int kStart, int kLen,
                                           f32x4 acc[2][2],
                                           unsigned short Ah[64][RP], unsigned short Al[64][RP],
                                           unsigned short Bh[64][RP], unsigned short Bl[64][RP]) {
    int tid = threadIdx.x;
    int w = tid >> 6, lane = tid & 63;
    int lm = lane & 15, quad = lane >> 4;
    int wm = (w & 1) * 32, wn = (w >> 1) * 32;
    int rA = tid >> 3, kcA = tid & 7;
    int rB = tid >> 2, kcB = tid & 3;
    for (int k0 = kStart; k0 < kStart + kLen; k0 += 32) {
#pragma unroll
        for (int i = 0; i < 2; ++i) {
            int r = rA + i * 32;
            const float4 av = *(const float4*)&A[(size_t)(rowBase + r) * K + k0 + kcA * 4];
            unsigned short h[4], l[4];
            split2(av.x, h[0], l[0]); split2(av.y, h[1], l[1]);
            split2(av.z, h[2], l[2]); split2(av.w, h[3], l[3]);
            unsigned long long ph = (unsigned long long)h[0] | ((unsigned long long)h[1] << 16)
                                  | ((unsigned long long)h[2] << 32) | ((unsigned long long)h[3] << 48);
            unsigned long long pl = (unsigned long long)l[0] | ((unsigned long long)l[1] << 16)
                                  | ((unsigned long long)l[2] << 32) | ((unsigned long long)l[3] << 48);
            *(unsigned long long*)&Ah[r][kcA * 4] = ph;
            *(unsigned long long*)&Al[r][kcA * 4] = pl;
        }
        {
            const short8 bvh = *(const short8*)&Bth[(size_t)(colBase + rB) * K + k0 + kcB * 8];
            *(short8*)&Bh[rB][kcB * 8] = bvh;
            const short8 bvl = *(const short8*)&Btl[(size_t)(colBase + rB) * K + k0 + kcB * 8];
            *(short8*)&Bl[rB][kcB * 8] = bvl;
        }
        __syncthreads();
        short8 ah[2], al[2], bh[2], bl[2];
#pragma unroll
        for (int t = 0; t < 2; ++t) {
            ah[t] = *(const short8*)&Ah[wm + t * 16 + lm][quad * 8];
            al[t] = *(const short8*)&Al[wm + t * 16 + lm][quad * 8];
            bh[t] = *(const short8*)&Bh[wn + t * 16 + lm][quad * 8];
            bl[t] = *(const short8*)&Bl[wn + t * 16 + lm][quad * 8];
        }
#pragma unroll
        for (int tm = 0; tm < 2; ++tm)
#pragma unroll
            for (int tn = 0; tn < 2; ++tn) {
                acc[tm][tn] = __builtin_amdgcn_mfma_f32_16x16x32_bf16(ah[tm], bh[tn], acc[tm][tn], 0, 0, 0);
                acc[tm][tn] = __builtin_amdgcn_mfma_f32_16x16x32_bf16(ah[tm], bl[tn], acc[tm][tn], 0, 0, 0);
                acc[tm][tn] = __builtin_amdgcn_mfma_f32_16x16x32_bf16(al[tm], bh[tn], acc[tm][tn], 0, 0, 0);
            }
        __syncthreads();
    }
}

__global__ __launch_bounds__(256) void mgemm_kernel(const float* __restrict__ A,
                                                    const unsigned short* __restrict__ Bth,
                                                    const unsigned short* __restrict__ Btl,
                                                    const float* __restrict__ bias,
                                                    float* __restrict__ C,
                                                    int N, int K, int relu) {
    __shared__ unsigned short Ah[64][RP], Al[64][RP], Bh[64][RP], Bl[64][RP];
    int tid = threadIdx.x;
    int w = tid >> 6, lane = tid & 63;
    int lm = lane & 15, quad = lane >> 4;
    int wm = (w & 1) * 32, wn = (w >> 1) * 32;
    int rowBase = blockIdx.y * 64, colBase = blockIdx.x * 64;
    f32x4 acc[2][2] = {};
    mgemm_core(A, Bth, Btl, K, rowBase, colBase, 0, K, acc, Ah, Al, Bh, Bl);
#pragma unroll
    for (int tm = 0; tm < 2; ++tm)
#pragma unroll
        for (int tn = 0; tn < 2; ++tn) {
            int col = colBase + wn + tn * 16 + lm;
            float bi = bias ? bias[col] : 0.f;
#pragma unroll
            for (int r = 0; r < 4; ++r) {
                int row = rowBase + wm + tm * 16 + quad * 4 + r;
                float v = acc[tm][tn][r] + bi;
                if (relu) v = fmaxf(v, 0.f);
                C[(size_t)row * N + col] = v;
            }
        }
}

__global__ __launch_bounds__(256) void mgemm_zw_kernel(const float* __restrict__ A,
                                                       const unsigned short* __restrict__ Bth,
                                                       const unsigned short* __restrict__ Btl,
                                                       const float* __restrict__ b0,
                                                       const float* __restrict__ b1,
                                                       const float* __restrict__ b2,
                                                       float* __restrict__ Cbase,
                                                       int M, int N, int K) {
    __shared__ unsigned short Ah[64][RP], Al[64][RP], Bh[64][RP], Bl[64][RP];
    int z = blockIdx.z;
    const unsigned short* bth = Bth + (size_t)z * K * N;
    const unsigned short* btl = Btl + (size_t)z * K * N;
    const float* bias = (z == 0) ? b0 : (z == 1) ? b1 : b2;
    float* C = Cbase + (size_t)z * M * N;
    int tid = threadIdx.x;
    int w = tid >> 6, lane = tid & 63;
    int lm = lane & 15, quad = lane >> 4;
    int wm = (w & 1) * 32, wn = (w >> 1) * 32;
    int rowBase = blockIdx.y * 64, colBase = blockIdx.x * 64;
    f32x4 acc[2][2] = {};
    mgemm_core(A, bth, btl, K, rowBase, colBase, 0, K, acc, Ah, Al, Bh, Bl);
#pragma unroll
    for (int tm = 0; tm < 2; ++tm)
#pragma unroll
        for (int tn = 0; tn < 2; ++tn) {
            int col = colBase + wn + tn * 16 + lm;
            float bi = bias ? bias[col] : 0.f;
#pragma unroll
            for (int r = 0; r < 4; ++r) {
                int row = rowBase + wm + tm * 16 + quad * 4 + r;
                C[(size_t)row * N + col] = acc[tm][tn][r] + bi;
            }
        }
}

// split-K: atomicAdd partials into C (caller ensures C holds the right base values).
__global__ __launch_bounds__(256) void mgemm_sk_kernel(const float* __restrict__ A,
                                                       const unsigned short* __restrict__ Bth,
                                                       const unsigned short* __restrict__ Btl,
                                                       const float* __restrict__ bias,
                                                       float* __restrict__ C,
                                                       int N, int K) {
    __shared__ unsigned short Ah[64][RP], Al[64][RP], Bh[64][RP], Bl[64][RP];
    int ks = gridDim.z, z = blockIdx.z;
    int kLen = K / ks, kStart = z * kLen;
    int tid = threadIdx.x;
    int w = tid >> 6, lane = tid & 63;
    int lm = lane & 15, quad = lane >> 4;
    int wm = (w & 1) * 32, wn = (w >> 1) * 32;
    int rowBase = blockIdx.y * 64, colBase = blockIdx.x * 64;
    f32x4 acc[2][2] = {};
    mgemm_core(A, Bth, Btl, K, rowBase, colBase, kStart, kLen, acc, Ah, Al, Bh, Bl);
#pragma unroll
    for (int tm = 0; tm < 2; ++tm)
#pragma unroll
        for (int tn = 0; tn < 2; ++tn) {
            int col = colBase + wn + tn * 16 + lm;
            float bi = (bias && z == 0) ? bias[col] : 0.f;
#pragma unroll
            for (int r = 0; r < 4; ++r) {
                int row = rowBase + wm + tm * 16 + quad * 4 + r;
                atomicAdd(&C[(size_t)row * N + col], acc[tm][tn][r] + bi);
            }
        }
}

// ---------------- LayerNorm 1 ----------------
__global__ void ln1_kernel(const float* __restrict__ x, const float* __restrict__ g,
                           const float* __restrict__ be, float* __restrict__ xn) {
    int row = blockIdx.x;
    int t = threadIdx.x;
    __shared__ float red[256];
    const float* xr = x + row * D_;
    float v0 = xr[t];
    float v1 = xr[t + 256];
    red[t] = v0 + v1;
    __syncthreads();
    for (int off = 128; off > 0; off >>= 1) {
        if (t < off) red[t] += red[t + off];
        __syncthreads();
    }
    float mean = red[0] * (1.0f / D_);
    __syncthreads();
    float d0 = v0 - mean, d1 = v1 - mean;
    red[t] = d0 * d0 + d1 * d1;
    __syncthreads();
    for (int off = 128; off > 0; off >>= 1) {
        if (t < off) red[t] += red[t + off];
        __syncthreads();
    }
    float rs = rsqrtf(red[0] * (1.0f / D_) + 1e-5f);
    float* o = xn + row * D_;
    o[t]       = d0 * rs * g[t]       + be[t];
    o[t + 256] = d1 * rs * g[t + 256] + be[t + 256];
}

// ---------------- Attention: one wave per (b,h,i); shuffle softmax ----------------
__global__ __launch_bounds__(256) void attn_kernel(const float* __restrict__ q,
                                                   const float* __restrict__ k,
                                                   const float* __restrict__ v,
                                                   float* __restrict__ attn,
                                                   float* __restrict__ ctx) {
    __shared__ float qsm[4][DH_];
    __shared__ float psm[4][S_];
    int w = threadIdx.x >> 6, lane = threadIdx.x & 63;
    int gid = blockIdx.x * 4 + w;         // (b*H + h)*S + i
    int i = gid & (S_ - 1);
    int bh = gid >> 7;
    int h = bh & (H_ - 1);
    int b = bh >> 3;
    const float* qrow = q + (size_t)(b * S_ + i) * D_ + h * DH_;
    qsm[w][lane] = qrow[lane & (DH_ - 1)];  // 64 lanes, 64 elems
    __syncthreads();
    // two scores per lane: j = lane, lane+64
    float s0 = 0.f, s1 = 0.f;
    const float* k0p = k + (size_t)(b * S_ + lane) * D_ + h * DH_;
    const float* k1p = k0p + (size_t)64 * D_;
#pragma unroll 8
    for (int d = 0; d < DH_; ++d) {
        float qd = qsm[w][d];
        s0 += qd * k0p[d];
        s1 += qd * k1p[d];
    }
    s0 *= 0.125f; s1 *= 0.125f;
    float m = fmaxf(s0, s1);
#pragma unroll
    for (int off = 32; off > 0; off >>= 1) m = fmaxf(m, __shfl_xor(m, off));
    float e0 = __expf(s0 - m), e1 = __expf(s1 - m);
    float sum = e0 + e1;
#pragma unroll
    for (int off = 32; off > 0; off >>= 1) sum += __shfl_xor(sum, off);
    float inv = 1.f / sum;
    float p0 = e0 * inv, p1 = e1 * inv;
    float* arow = attn + (size_t)gid * S_;
    arow[lane] = p0;
    arow[lane + 64] = p1;
    psm[w][lane] = p0;
    psm[w][lane + 64] = p1;
    __syncthreads();
    // ctx: lane = d
    const float* vbase = v + (size_t)b * S_ * D_ + h * DH_ + lane;
    float acc = 0.f;
    for (int j = 0; j < S_; ++j) acc += psm[w][j] * vbase[(size_t)j * D_];
    ctx[(size_t)(b * S_ + i) * D_ + h * DH_ + lane] = acc;
}

// ---------------- Adjacency + edge compaction ----------------
__global__ void adjc_kernel(const float* __restrict__ attn, int* __restrict__ ecount,
                            int* __restrict__ elist) {
    int idx = blockIdx.x * 256 + threadIdx.x;   // (b*S + i)*S + j
    if (idx >= B_ * S_ * S_) return;
    int j = idx & (S_ - 1);
    int bi = idx >> 7;
    int i = bi & (S_ - 1);
    int b = bi >> 7;
    float s = 0.f;
#pragma unroll
    for (int h = 0; h < H_; ++h) s += attn[(((size_t)(b * H_ + h)) * S_ + i) * S_ + j];
    s *= (1.0f / H_);
    if (s > 0.1f && i != j) {
        int p = atomicAdd(ecount, 1);
        elist[p] = idx;
    }
}

// ---------------- Relation classifier over compacted edges ----------------
__global__ __launch_bounds__(64) void edge_kernel(const float* __restrict__ a_part,
                                                  const float* __restrict__ b_part,
                                                  const float* __restrict__ rc_b1,
                                                  const float* __restrict__ rc_w2,
                                                  const float* __restrict__ rc_b2,
                                                  const int* __restrict__ elist,
                                                  const int* __restrict__ ecount,
                                                  int* __restrict__ rel) {
    int lane = threadIdx.x;
    int n = *ecount;
    for (int e = blockIdx.x; e < n; e += gridDim.x) {
        int idx = elist[e];
        int vv = idx & (S_ - 1);
        int bu = idx >> 7;
        int u = bu & (S_ - 1);
        int b = bu >> 7;
        const float* ap = a_part + (size_t)(b * S_ + u) * D_;
        const float* bp = b_part + (size_t)(b * S_ + vv) * D_;
        float lp[R_];
#pragma unroll
        for (int r = 0; r < R_; ++r) lp[r] = 0.f;
#pragma unroll
        for (int jj = 0; jj < D_ / 64; ++jj) {
            int d = lane + jj * 64;
            float hv = fmaxf(ap[d] + bp[d] + rc_b1[d], 0.f);
#pragma unroll
            for (int r = 0; r < R_; ++r) lp[r] += hv * rc_w2[d * R_ + r];
        }
#pragma unroll
        for (int r = 0; r < R_; ++r) {
#pragma unroll
            for (int off = 32; off > 0; off >>= 1) lp[r] += __shfl_down(lp[r], off);
        }
        if (lane == 0) {
            float best = lp[0] + rc_b2[0];
            int bi = 0;
#pragma unroll
            for (int r = 1; r < R_; ++r) {
                float L = lp[r] + rc_b2[r];
                if (L > best) { best = L; bi = r; }
            }
            rel[idx] = bi;
        }
    }
}

// ---------------- mbuild: LDS accumulate, single write ----------------
__global__ __launch_bounds__(128) void mbuild_kernel(const float* __restrict__ nu,
                                                     const int* __restrict__ rel,
                                                     float* __restrict__ M) {
    __shared__ float acc[R_ * D_];   // 16 KB
    __shared__ int rl[S_];
    int blk = blockIdx.x;            // b*S + v
    int vv = blk & (S_ - 1);
    int b = blk >> 7;
    int t = threadIdx.x;             // 128
    for (int i = t; i < R_ * D_; i += 128) acc[i] = 0.f;
    rl[t] = rel[((size_t)b * S_ + t) * S_ + vv];
    __syncthreads();
    for (int u = 0; u < S_; ++u) {
        int r = rl[u];
        if (r > 0) {
            const float* nurow = nu + (size_t)(b * S_ + u) * D_;
            float* arow = acc + r * D_;
#pragma unroll
            for (int jj = 0; jj < D_ / 128; ++jj) arow[t + jj * 128] += nurow[t + jj * 128];
        }
    }
    __syncthreads();
    float* Mrow = M + (size_t)blk * (R_ * D_);
    for (int i = t; i < R_ * D_; i += 128) Mrow[i] = acc[i];
}

// ---------------- LayerNorm 2 -> fp32 out ----------------
__global__ void ln2_kernel(const float* __restrict__ x, const float* __restrict__ y,
                           const float* __restrict__ g, const float* __restrict__ be,
                           float* __restrict__ out) {
    int row = blockIdx.x;
    int t = threadIdx.x;
    __shared__ float red[256];
    float v0 = x[row * D_ + t]       + y[row * D_ + t];
    float v1 = x[row * D_ + t + 256] + y[row * D_ + t + 256];
    red[t] = v0 + v1;
    __syncthreads();
    for (int off = 128; off > 0; off >>= 1) {
        if (t < off) red[t] += red[t + off];
        __syncthreads();
    }
    float mean = red[0] * (1.0f / D_);
    __syncthreads();
    float d0 = v0 - mean, d1 = v1 - mean;
    red[t] = d0 * d0 + d1 * d1;
    __syncthreads();
    for (int off = 128; off > 0; off >>= 1) {
        if (t < off) red[t] += red[t + off];
        __syncthreads();
    }
    float rs = rsqrtf(red[0] * (1.0f / D_) + 1e-5f);
    out[row * D_ + t]       = d0 * rs * g[t]       + be[t];
    out[row * D_ + t + 256] = d1 * rs * g[t + 256] + be[t + 256];
}

extern "C" void kernel_launch(void* const* d_in, const int* in_sizes, int n_in,
                              void* d_out, int out_size, void* d_ws, size_t ws_size,
                              hipStream_t stream) {
    const float* x     = (const float*)d_in[0];
    const float* ln1_g = (const float*)d_in[1];
    const float* ln1_b = (const float*)d_in[2];
    const float* wq    = (const float*)d_in[3];
    const float* bq    = (const float*)d_in[4];
    const float* wk    = (const float*)d_in[5];
    const float* bk    = (const float*)d_in[6];
    const float* wv    = (const float*)d_in[7];
    const float* bv    = (const float*)d_in[8];
    const float* wo    = (const float*)d_in[9];
    const float* bo    = (const float*)d_in[10];
    const float* w1    = (const float*)d_in[11];
    const float* b1    = (const float*)d_in[12];
    const float* w2    = (const float*)d_in[13];
    const float* b2    = (const float*)d_in[14];
    const float* rc_w1 = (const float*)d_in[15];
    const float* rc_b1 = (const float*)d_in[16];
    const float* rc_w2 = (const float*)d_in[17];
    const float* rc_b2 = (const float*)d_in[18];
    const float* kg_w  = (const float*)d_in[19];
    const float* s2n_w = (const float*)d_in[20];
    const float* s2n_b = (const float*)d_in[21];
    const float* ln2_g = (const float*)d_in[22];
    const float* ln2_b = (const float*)d_in[23];
    float* out = (float*)d_out;

    const int BS  = B_ * S_;          // 512
    const int BSD = BS * D_;          // 262144

    // ---- Workspace (ws_size = 256 MB per harness fill evidence) ----
    unsigned short* wt = (unsigned short*)d_ws;
    const size_t E = 262144;          // 512*512
    unsigned short* qkv_h = wt;
    unsigned short* qkv_l = wt + 3 * E;
    unsigned short* wo_h  = wt + 6 * E;
    unsigned short* wo_l  = wt + 7 * E;
    unsigned short* w1_h  = wt + 8 * E;
    unsigned short* w1_l  = wt + 12 * E;
    unsigned short* w2_h  = wt + 16 * E;
    unsigned short* w2_l  = wt + 20 * E;
    unsigned short* rc_h  = wt + 24 * E;
    unsigned short* rc_l  = wt + 26 * E;
    unsigned short* kg_h  = wt + 28 * E;
    unsigned short* kg_l  = wt + 36 * E;
    unsigned short* s2_h  = wt + 44 * E;
    unsigned short* s2_l  = wt + 45 * E;
    size_t wt_words = 46 * E;

    int* rel    = (int*)(wt + wt_words);        // 65536 ints (pre-zeroed)
    int* ecount = rel + B_ * S_ * S_;           // 64 ints (pre-zeroed with rel)
    int* elist  = ecount + 64;                  // 65536 ints
    float* BIG  = (float*)(elist + B_ * S_ * S_);
    float* S0   = BIG + 2097152;
    float* S1   = S0 + BSD;
    float* S2   = S1 + BSD;
    float* S3   = S2 + BSD;
    float* S4   = S3 + BSD;

    float* xn       = S0;
    float* q        = S1;   // q,k,v in S1,S2,S3
    float* v_       = S3;
    float* attn     = BIG;
    float* ctx      = S4;
    float* attn_out = S0;
    float* hidden   = BIG;
    float* nu       = S2;
    float* a_part   = S0;   // a_part,b_part in S0,S1
    float* Mbuf     = BIG;
    float* y        = S0;

    // 0a. zero rel + ecount
    hipMemsetAsync(rel, 0, (size_t)(B_ * S_ * S_ + 64) * 4, stream);
    // 0b. transpose+split all weights
    TPack tp;
    int off = 0;
    auto setd = [&](int i, const float* s, unsigned short* h, unsigned short* l, int K, int N) {
        tp.d[i] = TDesc{s, h, l, K, N, off};
        off += (K / 32) * (N / 32);
    };
    setd(0, wq, qkv_h,         qkv_l,         D_, D_);
    setd(1, wk, qkv_h + E,     qkv_l + E,     D_, D_);
    setd(2, wv, qkv_h + 2 * E, qkv_l + 2 * E, D_, D_);
    setd(3, wo, wo_h, wo_l, D_, D_);
    setd(4, w1, w1_h, w1_l, D_, F_);
    setd(5, w2, w2_h, w2_l, F_, D_);
    setd(6, rc_w1,            rc_h,     rc_l,     D_, D_);
    setd(7, rc_w1 + D_ * D_,  rc_h + E, rc_l + E, D_, D_);
    setd(8, kg_w, kg_h, kg_l, R_ * D_, D_);
    setd(9, s2n_w, s2_h, s2_l, D_, D_);
    hipLaunchKernelGGL(transpose_split_kernel, dim3(off), dim3(256), 0, stream, tp);

    // 1. LN1
    hipLaunchKernelGGL(ln1_kernel, dim3(BS), dim3(256), 0, stream, x, ln1_g, ln1_b, xn);
    // 2. QKV (z-batched) -> S1,S2,S3
    hipLaunchKernelGGL(mgemm_zw_kernel, dim3(D_ / 64, BS / 64, 3), dim3(256), 0, stream,
                       xn, qkv_h, qkv_l, bq, bk, bv, q, BS, D_, D_);
    // 3. attention (wave-per-row) -> attn(BIG), ctx(S4)
    hipLaunchKernelGGL(attn_kernel, dim3(B_ * H_ * S_ / 4), dim3(256), 0, stream,
                       q, q + BSD, v_, attn, ctx);
    hipMemsetAsync(nu, 0, (size_t)BSD * 4, stream);   // k dead; FFN2 atomic target
    // 4. adjacency + edge compaction
    hipLaunchKernelGGL(adjc_kernel, dim3(B_ * S_ * S_ / 256), dim3(256), 0, stream,
                       attn, ecount, elist);
    // 5. wo: ctx -> attn_out
    hipLaunchKernelGGL(mgemm_kernel, dim3(D_ / 64, BS / 64), dim3(256), 0, stream,
                       ctx, wo_h, wo_l, bo, attn_out, D_, D_, 0);
    // 6. FFN1 (relu): attn_out -> hidden
    hipLaunchKernelGGL(mgemm_kernel, dim3(F_ / 64, BS / 64), dim3(256), 0, stream,
                       attn_out, w1_h, w1_l, b1, hidden, F_, D_, 1);
    // 7. FFN2 split-K=4 -> nu (zeroed)
    hipLaunchKernelGGL(mgemm_sk_kernel, dim3(D_ / 64, BS / 64, 4), dim3(256), 0, stream,
                       hidden, w2_h, w2_l, b2, nu, D_, F_);
    // 8. rc halves (z-batched) -> a_part,b_part
    hipLaunchKernelGGL(mgemm_zw_kernel, dim3(D_ / 64, BS / 64, 2), dim3(256), 0, stream,
                       nu, rc_h, rc_l, (const float*)nullptr, (const float*)nullptr,
                       (const float*)nullptr, a_part, BS, D_, D_);
    // 9. edges (persistent over compacted list)
    hipLaunchKernelGGL(edge_kernel, dim3(256), dim3(64), 0, stream,
                       a_part, a_part + BSD, rc_b1, rc_w2, rc_b2, elist, ecount, rel);
    // 10. RGCN aggregate (LDS) -> Mbuf
    hipLaunchKernelGGL(mbuild_kernel, dim3(BS), dim3(128), 0, stream, nu, rel, Mbuf);
    // 11. Mbuf @ kg_w split-K=8, atomicAdd directly into nu (reasoned = nu + agg)
    hipLaunchKernelGGL(mgemm_sk_kernel, dim3(D_ / 64, BS / 64, 8), dim3(256), 0, stream,
                       Mbuf, kg_h, kg_l, (const float*)nullptr, nu, D_, R_ * D_);
    // 13. s2n: nu -> y
    hipLaunchKernelGGL(mgemm_kernel, dim3(D_ / 64, BS / 64), dim3(256), 0, stream,
                       nu, s2_h, s2_l, s2n_b, y, D_, D_, 0);
    // 14. LN2 -> out
    hipLaunchKernelGGL(ln2_kernel, dim3(BS), dim3(256), 0, stream, x, y, ln2_g, ln2_b, out);
}